// Round 2
// baseline (144.381 us; speedup 1.0000x reference)
//
#include <hip/hip_runtime.h>

// LengthRegulator: b=16, t_x=1024, d=256, out_len=7168 (fixed by setup_inputs)
#define B       16
#define TX      1024
#define D       256
#define OUT_LEN 7168
#define TILE    16          // output rows per block in expand kernel

// Native 16B vector type — __builtin_nontemporal_* requires a scalar/vector
// type, not HIP's float4 class.
typedef float v4f __attribute__((ext_vector_type(4)));

// ---------------------------------------------------------------------------
// Kernel 1: per-batch inclusive scan of repeat_count (shfl wave-scan, single
// barrier), lengths (as float) into the tail of d_out, AND inverse-map
// scatter: src[b][j] = i for j in [cum[i-1], cum[i]), sentinel 0xFFFF for
// tail rows. This removes the per-output-row binary search from the hot
// expand kernel entirely.
// One block per batch, 256 threads, 4 inputs per thread.
// ---------------------------------------------------------------------------
__global__ __launch_bounds__(256) void lr_scan_scatter_kernel(
        const int* __restrict__ rc,           // (B, TX) int32
        unsigned short* __restrict__ src,     // (B, OUT_LEN) ushort ws
        float* __restrict__ len_out)          // d_out + B*OUT_LEN*D, B floats
{
    __shared__ int wtot[4];
    const int b = blockIdx.x;
    const int t = threadIdx.x;

    const int4 v = ((const int4*)(rc + b * TX))[t];
    const int s0 = v.x;
    const int s1 = s0 + v.y;
    const int s2 = s1 + v.z;
    const int s3 = s2 + v.w;

    // Init this batch's src row to sentinel (tail rows -> zero output).
    // 7168 ushorts = 1792 uint2 = 256 threads x 7.
    uint2* srow8 = (uint2*)(src + (size_t)b * OUT_LEN);
    const uint2 ff = make_uint2(0xFFFFFFFFu, 0xFFFFFFFFu);
    #pragma unroll
    for (int k = 0; k < OUT_LEN / (4 * 256); ++k)   // 7 iters
        srow8[t + 256 * k] = ff;

    // Wave-level inclusive scan of per-thread sums (no barriers).
    int wscan = s3;
    #pragma unroll
    for (int off = 1; off < 64; off <<= 1) {
        int n = __shfl_up(wscan, off, 64);
        if ((t & 63) >= off) wscan += n;
    }
    if ((t & 63) == 63) wtot[t >> 6] = wscan;
    // Single barrier: publishes wave totals AND (compiler drains vmcnt before
    // s_barrier) orders the sentinel init stores before the scatter below.
    __syncthreads();

    int wexcl = 0;
    #pragma unroll
    for (int w = 0; w < 3; ++w)
        if (w < (t >> 6)) wexcl += wtot[w];
    const int incl = wexcl + wscan;      // inclusive prefix over 4-elem groups
    const int excl = incl - s3;          // exclusive prefix before input 4t

    if (t == 255) len_out[b] = (float)incl;   // lengths[b]

    // Scatter: input i covers output rows [start_i, start_i + rc_i).
    unsigned short* s = src + (size_t)b * OUT_LEN;
    const int i0 = 4 * t;
    const int ofs[4] = {excl, excl + s0, excl + s1, excl + s2};
    const int cnt[4] = {v.x, v.y, v.z, v.w};
    #pragma unroll
    for (int e = 0; e < 4; ++e)
        for (int k = 0; k < cnt[e]; ++k)
            s[ofs[e] + k] = (unsigned short)(i0 + e);
}

// ---------------------------------------------------------------------------
// Kernel 2: expand — now a pure streaming copy. Each block handles TILE
// consecutive output rows of one batch; each wave owns 4 rows. Per row:
// one wave-uniform ushort read (src index), one coalesced 1KB float4 load,
// one coalesced 1KB non-temporal float4 store. No LDS, no barrier, no search.
// ---------------------------------------------------------------------------
__global__ __launch_bounds__(256) void lr_expand_kernel(
        const float* __restrict__ x,            // (B, TX, D)
        const unsigned short* __restrict__ src, // (B, OUT_LEN)
        float* __restrict__ out)                // (B, OUT_LEN, D)
{
    const int blocks_per_batch = OUT_LEN / TILE;   // 448
    const int b    = blockIdx.x / blocks_per_batch;
    const int row0 = (blockIdx.x % blocks_per_batch) * TILE;
    const int t    = threadIdx.x;
    const int lane4 = t & 63;   // float4 slot within the row (64 * 16B = 1KB)
    const int sub   = t >> 6;   // which of 4 waves; each wave owns 4 rows

    const v4f* x4 = (const v4f*)(x + (size_t)b * TX * D);
    v4f*     out4 = (v4f*)(out + (size_t)b * OUT_LEN * D);
    const unsigned short* srow = src + (size_t)b * OUT_LEN + row0;

    // Prefetch the 4 source indices for this wave (wave-uniform broadcasts);
    // issued up-front so the 4 row copies pipeline independently.
    int idx[4];
    #pragma unroll
    for (int e = 0; e < 4; ++e)
        idx[e] = srow[sub + 4 * e];

    #pragma unroll
    for (int e = 0; e < 4; ++e) {
        const int j = row0 + sub + 4 * e;
        const int i = idx[e];
        v4f val = (v4f)(0.f);
        if (i != 0xFFFF)
            val = __builtin_nontemporal_load(&x4[(size_t)i * (D / 4) + lane4]);
        // Output is written once and never re-read: non-temporal store keeps
        // L2 free for x.
        __builtin_nontemporal_store(val, &out4[(size_t)j * (D / 4) + lane4]);
    }
}

extern "C" void kernel_launch(void* const* d_in, const int* in_sizes, int n_in,
                              void* d_out, int out_size, void* d_ws, size_t ws_size,
                              hipStream_t stream) {
    const float* x  = (const float*)d_in[0];
    const int*   rc = (const int*)d_in[1];     // repeat_count (int32 on device)
    float* out = (float*)d_out;
    float* len_out = out + (size_t)B * OUT_LEN * D;   // lengths chunk (B floats)
    unsigned short* src = (unsigned short*)d_ws;      // (B, OUT_LEN) ushort scratch

    lr_scan_scatter_kernel<<<B, 256, 0, stream>>>(rc, src, len_out);

    const int grid = B * (OUT_LEN / TILE);            // 7168 blocks
    lr_expand_kernel<<<grid, 256, 0, stream>>>(x, src, out);
}

// Round 3
// 143.504 us; speedup vs baseline: 1.0061x; 1.0061x over previous
//
#include <hip/hip_runtime.h>

// LengthRegulator: b=16, t_x=1024, d=256, out_len=7168 (fixed by setup_inputs)
#define B       16
#define TX      1024
#define D       256
#define OUT_LEN 7168
#define TILE    16          // output rows per block in expand kernel

// Native 16B vector type — __builtin_nontemporal_* requires a scalar/vector
// type, not HIP's float4 class.
typedef float v4f __attribute__((ext_vector_type(4)));

// ---------------------------------------------------------------------------
// Kernel 1: per-batch inclusive scan of repeat_count (shfl wave-scan, single
// barrier), lengths (as float) into the tail of d_out, AND inverse-map
// scatter: src[b][j] = i for j in [cum[i-1], cum[i]), sentinel 0xFFFF for
// tail rows. This removes the per-output-row binary search from the hot
// expand kernel entirely.
// One block per batch, 256 threads, 4 inputs per thread.
// ---------------------------------------------------------------------------
__global__ __launch_bounds__(256) void lr_scan_scatter_kernel(
        const int* __restrict__ rc,           // (B, TX) int32
        unsigned short* __restrict__ src,     // (B, OUT_LEN) ushort ws
        float* __restrict__ len_out)          // d_out + B*OUT_LEN*D, B floats
{
    __shared__ int wtot[4];
    const int b = blockIdx.x;
    const int t = threadIdx.x;

    const int4 v = ((const int4*)(rc + b * TX))[t];
    const int s0 = v.x;
    const int s1 = s0 + v.y;
    const int s2 = s1 + v.z;
    const int s3 = s2 + v.w;

    // Init this batch's src row to sentinel (tail rows -> zero output).
    // 7168 ushorts = 1792 uint2 = 256 threads x 7.
    uint2* srow8 = (uint2*)(src + (size_t)b * OUT_LEN);
    const uint2 ff = make_uint2(0xFFFFFFFFu, 0xFFFFFFFFu);
    #pragma unroll
    for (int k = 0; k < OUT_LEN / (4 * 256); ++k)   // 7 iters
        srow8[t + 256 * k] = ff;

    // Wave-level inclusive scan of per-thread sums (no barriers).
    int wscan = s3;
    #pragma unroll
    for (int off = 1; off < 64; off <<= 1) {
        int n = __shfl_up(wscan, off, 64);
        if ((t & 63) >= off) wscan += n;
    }
    if ((t & 63) == 63) wtot[t >> 6] = wscan;
    // Single barrier: publishes wave totals AND (compiler drains vmcnt before
    // s_barrier) orders the sentinel init stores before the scatter below.
    __syncthreads();

    int wexcl = 0;
    #pragma unroll
    for (int w = 0; w < 3; ++w)
        if (w < (t >> 6)) wexcl += wtot[w];
    const int incl = wexcl + wscan;      // inclusive prefix over 4-elem groups
    const int excl = incl - s3;          // exclusive prefix before input 4t

    if (t == 255) len_out[b] = (float)incl;   // lengths[b]

    // Scatter: input i covers output rows [start_i, start_i + rc_i).
    unsigned short* s = src + (size_t)b * OUT_LEN;
    const int i0 = 4 * t;
    const int ofs[4] = {excl, excl + s0, excl + s1, excl + s2};
    const int cnt[4] = {v.x, v.y, v.z, v.w};
    #pragma unroll
    for (int e = 0; e < 4; ++e)
        for (int k = 0; k < cnt[e]; ++k)
            s[ofs[e] + k] = (unsigned short)(i0 + e);
}

// ---------------------------------------------------------------------------
// Kernel 2: expand — pure streaming copy. Each block handles TILE
// consecutive output rows of one batch; each wave owns 4 rows. Per row:
// one wave-uniform ushort read (src index), one coalesced 1KB float4 load
// (CACHED — x rows are reused ~3.5x, keep them in L2; NT load here cost
// ~+40MB HBM refetch in R2), one coalesced 1KB non-temporal float4 store
// (out is write-once, bypass L2). No LDS, no barrier, no search.
// ---------------------------------------------------------------------------
__global__ __launch_bounds__(256) void lr_expand_kernel(
        const float* __restrict__ x,            // (B, TX, D)
        const unsigned short* __restrict__ src, // (B, OUT_LEN)
        float* __restrict__ out)                // (B, OUT_LEN, D)
{
    const int blocks_per_batch = OUT_LEN / TILE;   // 448
    const int b    = blockIdx.x / blocks_per_batch;
    const int row0 = (blockIdx.x % blocks_per_batch) * TILE;
    const int t    = threadIdx.x;
    const int lane4 = t & 63;   // float4 slot within the row (64 * 16B = 1KB)
    const int sub   = t >> 6;   // which of 4 waves; each wave owns 4 rows

    const v4f* x4 = (const v4f*)(x + (size_t)b * TX * D);
    v4f*     out4 = (v4f*)(out + (size_t)b * OUT_LEN * D);
    const unsigned short* srow = src + (size_t)b * OUT_LEN + row0;

    // Prefetch the 4 source indices for this wave (wave-uniform broadcasts);
    // issued up-front so the 4 row copies pipeline independently.
    int idx[4];
    #pragma unroll
    for (int e = 0; e < 4; ++e)
        idx[e] = srow[sub + 4 * e];

    #pragma unroll
    for (int e = 0; e < 4; ++e) {
        const int j = row0 + sub + 4 * e;
        const int i = idx[e];
        v4f val = (v4f)(0.f);
        if (i != 0xFFFF)
            val = x4[(size_t)i * (D / 4) + lane4];   // cached load (reused)
        // Output is written once and never re-read: non-temporal store keeps
        // L2 free for x.
        __builtin_nontemporal_store(val, &out4[(size_t)j * (D / 4) + lane4]);
    }
}

extern "C" void kernel_launch(void* const* d_in, const int* in_sizes, int n_in,
                              void* d_out, int out_size, void* d_ws, size_t ws_size,
                              hipStream_t stream) {
    const float* x  = (const float*)d_in[0];
    const int*   rc = (const int*)d_in[1];     // repeat_count (int32 on device)
    float* out = (float*)d_out;
    float* len_out = out + (size_t)B * OUT_LEN * D;   // lengths chunk (B floats)
    unsigned short* src = (unsigned short*)d_ws;      // (B, OUT_LEN) ushort scratch

    lr_scan_scatter_kernel<<<B, 256, 0, stream>>>(rc, src, len_out);

    const int grid = B * (OUT_LEN / TILE);            // 7168 blocks
    lr_expand_kernel<<<grid, 256, 0, stream>>>(x, src, out);
}